// Round 1
// baseline (15904.462 us; speedup 1.0000x reference)
//
#include <hip/hip_runtime.h>
#include <math.h>

namespace {

constexpr int NB = 1024;   // batch
constexpr int ND = 512;    // XDIM
constexpr int NH = 1024;   // hidden
constexpr int NSTEPS_C = 10;

__device__ __forceinline__ float wrap_angle(float x) {
  const float PI_F = 3.14159265358979323846f;
  const float TWO_PI = 6.28318530717958647692f;
  const float INV_TWO_PI = 0.15915494309189533577f;
  float y = x + PI_F;
  float r = y - TWO_PI * floorf(y * INV_TWO_PI);
  return r - PI_F;
}

// ---------------------------------------------------------------------------
// Generic fused GEMM: out = act( concat(A0, mask?*A1) @ W + bias )
// M=1024 rows, K=1024 (two 512 halves), N = 64*gridDim.x, tile 64x64,
// 256 threads, 4x4 outputs/thread, f32.
// ---------------------------------------------------------------------------
__device__ __forceinline__ void gemm_body(
    const float* __restrict__ A0, int lda0,
    const float* __restrict__ A1, int lda1,
    const float* __restrict__ maskp, int maskInv,
    const float* __restrict__ W, int ldw,
    const float* __restrict__ bias,
    float* __restrict__ out, int ldo, int act,
    int bx, int by)
{
  __shared__ float As[32 * 68];   // transposed A tile [k][row], stride 68
  __shared__ float Bs[32 * 64];   // B tile [k][n]
  const int tid = threadIdx.x;
  const int ty = tid >> 4, tx = tid & 15;
  const int row0 = by * 64, col0 = bx * 64;
  float acc[4][4] = {{0.f, 0.f, 0.f, 0.f}, {0.f, 0.f, 0.f, 0.f},
                     {0.f, 0.f, 0.f, 0.f}, {0.f, 0.f, 0.f, 0.f}};

  for (int kt = 0; kt < 1024 / 32; ++kt) {
    const int kbase = kt * 32;
    // A tile: 64 rows x 32 k, float4 along k, store transposed into LDS
#pragma unroll
    for (int h = 0; h < 2; ++h) {
      int f = tid + h * 256;
      int r = f >> 3;            // 0..63 local row
      int k0 = (f & 7) << 2;     // 0..28 local k
      int gk = kbase + k0;       // global k in [0,1024)
      float4 a;
      if (gk < 512) {
        a = *reinterpret_cast<const float4*>(A0 + (size_t)(row0 + r) * lda0 + gk);
      } else {
        int kk = gk - 512;
        a = *reinterpret_cast<const float4*>(A1 + (size_t)(row0 + r) * lda1 + kk);
        if (maskp) {
          float4 mv = *reinterpret_cast<const float4*>(maskp + kk);
          float m0 = maskInv ? 1.f - mv.x : mv.x;
          float m1 = maskInv ? 1.f - mv.y : mv.y;
          float m2 = maskInv ? 1.f - mv.z : mv.z;
          float m3 = maskInv ? 1.f - mv.w : mv.w;
          a.x *= m0; a.y *= m1; a.z *= m2; a.w *= m3;
        }
      }
      As[(k0 + 0) * 68 + r] = a.x;
      As[(k0 + 1) * 68 + r] = a.y;
      As[(k0 + 2) * 68 + r] = a.z;
      As[(k0 + 3) * 68 + r] = a.w;
    }
    // B tile: 32 k x 64 n, float4 along n
#pragma unroll
    for (int h = 0; h < 2; ++h) {
      int f = tid + h * 256;
      int kr = f >> 4;           // 0..31
      int n4 = (f & 15) << 2;    // 0..60
      *reinterpret_cast<float4*>(&Bs[kr * 64 + n4]) =
          *reinterpret_cast<const float4*>(W + (size_t)(kbase + kr) * ldw + col0 + n4);
    }
    __syncthreads();
#pragma unroll
    for (int kr = 0; kr < 32; ++kr) {
      float4 a4 = *reinterpret_cast<const float4*>(&As[kr * 68 + ty * 4]);
      float4 b4 = *reinterpret_cast<const float4*>(&Bs[kr * 64 + tx * 4]);
      float av[4] = {a4.x, a4.y, a4.z, a4.w};
      float bv[4] = {b4.x, b4.y, b4.z, b4.w};
#pragma unroll
      for (int i = 0; i < 4; ++i)
#pragma unroll
        for (int j = 0; j < 4; ++j)
          acc[i][j] = fmaf(av[i], bv[j], acc[i][j]);
    }
    __syncthreads();
  }

  float4 bv4 = *reinterpret_cast<const float4*>(bias + col0 + tx * 4);
  float bb[4] = {bv4.x, bv4.y, bv4.z, bv4.w};
#pragma unroll
  for (int i = 0; i < 4; ++i) {
    float o[4];
#pragma unroll
    for (int j = 0; j < 4; ++j) {
      float vl = acc[i][j] + bb[j];
      if (act) vl = tanhf(vl);
      o[j] = vl;
    }
    *reinterpret_cast<float4*>(out + (size_t)(row0 + ty * 4 + i) * ldo + col0 + tx * 4) =
        make_float4(o[0], o[1], o[2], o[3]);
  }
}

__global__ __launch_bounds__(256) void gemm64(
    const float* A0, int lda0, const float* A1, int lda1,
    const float* maskp, int maskInv,
    const float* W, int ldw, const float* bias,
    float* out, int ldo, int act)
{
  gemm_body(A0, lda0, A1, lda1, maskp, maskInv, W, ldw, bias, out, ldo, act,
            blockIdx.x, blockIdx.y);
}

// S, T, Q heads in one launch (gridDim.z = 3). act: tanh on S and Q only.
__global__ __launch_bounds__(256) void stq_gemm(
    const float* h2,
    const float* Ws, const float* bs_,
    const float* Wt, const float* bt_,
    const float* Wq, const float* bq_,
    float* S, float* T, float* Q)
{
  int z = blockIdx.z;
  const float* W = (z == 0) ? Ws : ((z == 1) ? Wt : Wq);
  const float* bb = (z == 0) ? bs_ : ((z == 1) ? bt_ : bq_);
  float* o = (z == 0) ? S : ((z == 1) ? T : Q);
  gemm_body(h2, NH, h2 + ND, NH, nullptr, 0, W, ND, bb, o, ND,
            (z == 1) ? 0 : 1, blockIdx.x, blockIdx.y);
}

// ---------------------------------------------------------------------------
// grad of action: g = d/dx [ beta * sum(1 - cos(plaq)) ], one block per sample
// x layout per sample: [(t*16+l)*2 + d], t,l in [0,16), d in {0,1}
// p[t,l] = x[t,l,0] - x[t,l,1] - x[t,l+1,0] + x[t+1,l,1]  (periodic)
// g[t,l,0] = beta*(sin p[t,l] - sin p[t,l-1])
// g[t,l,1] = beta*(sin p[t-1,l] - sin p[t,l])
// ---------------------------------------------------------------------------
__global__ __launch_bounds__(256) void grad_kernel(
    const float* __restrict__ x, float* __restrict__ g,
    const float* __restrict__ betap)
{
  __shared__ float xs[512];
  __shared__ float sp[256];
  int b = blockIdx.x, t = threadIdx.x;
  const float* xr = x + (size_t)b * ND;
  xs[t] = xr[t];
  xs[t + 256] = xr[t + 256];
  __syncthreads();
  int tt = t >> 4, l = t & 15;
  float p = xs[t * 2] - xs[t * 2 + 1]
          - xs[(tt * 16 + ((l + 1) & 15)) * 2]
          + xs[(((tt + 1) & 15) * 16 + l) * 2 + 1];
  sp[t] = sinf(p);
  __syncthreads();
  float beta = betap[0];
  float g0 = beta * (sp[t] - sp[tt * 16 + ((l - 1) & 15)]);
  float g1 = beta * (sp[((tt - 1) & 15) * 16 + l] - sp[t]);
  float* gr = g + (size_t)b * ND;
  gr[t * 2] = g0;
  gr[t * 2 + 1] = g1;
}

// ---------------------------------------------------------------------------
// v update (fwd: v = v*e^{sc} - 0.5 eps (g e^{eps Q} + T), sc = +0.5 eps S)
//          (bwd: v = e^{sc} (v + 0.5 eps (g e^{eps Q} + T)), sc = -0.5 eps S)
// ld[row] += sum(sc). One block (128 thr) per row.
// ---------------------------------------------------------------------------
__global__ __launch_bounds__(128) void upd_v_kernel(
    float* __restrict__ v, const float* __restrict__ g,
    const float* __restrict__ S, const float* __restrict__ Tt,
    const float* __restrict__ Q,
    const float* __restrict__ epsp, float* __restrict__ ld, int fwd)
{
  int row = blockIdx.x;
  int c = threadIdx.x << 2;
  size_t off = (size_t)row * ND + c;
  float eps = epsp[0];
  float4 v4 = *reinterpret_cast<float4*>(v + off);
  float4 g4 = *reinterpret_cast<const float4*>(g + off);
  float4 s4 = *reinterpret_cast<const float4*>(S + off);
  float4 t4 = *reinterpret_cast<const float4*>(Tt + off);
  float4 q4 = *reinterpret_cast<const float4*>(Q + off);
  float vv[4] = {v4.x, v4.y, v4.z, v4.w};
  float gg[4] = {g4.x, g4.y, g4.z, g4.w};
  float ss[4] = {s4.x, s4.y, s4.z, s4.w};
  float tz[4] = {t4.x, t4.y, t4.z, t4.w};
  float qq[4] = {q4.x, q4.y, q4.z, q4.w};
  float scsum = 0.f;
#pragma unroll
  for (int j = 0; j < 4; ++j) {
    float sc = (fwd ? 0.5f : -0.5f) * eps * ss[j];
    float F = gg[j] * expf(eps * qq[j]) + tz[j];
    vv[j] = fwd ? vv[j] * expf(sc) - 0.5f * eps * F
                : expf(sc) * (vv[j] + 0.5f * eps * F);
    scsum += sc;
  }
  *reinterpret_cast<float4*>(v + off) = make_float4(vv[0], vv[1], vv[2], vv[3]);
  for (int o = 32; o > 0; o >>= 1) scsum += __shfl_down(scsum, o);
  __shared__ float part[2];
  if ((threadIdx.x & 63) == 0) part[threadIdx.x >> 6] = scsum;
  __syncthreads();
  if (threadIdx.x == 0) ld[row] += part[0] + part[1];
}

// ---------------------------------------------------------------------------
// x update. m_eff = maskInv ? 1-m : m ; mb = 1-m_eff.
// fwd: xn = m*x + mb*(x e^{eps S} + eps (v e^{eps Q} + T));  ld += sum(mb*eps*S)
// bwd: xn = m*x + mb*e^{-eps S}*(x - eps (v e^{eps Q} + T)); ld -= sum(mb*eps*S)
// wrap to [-pi,pi).
// ---------------------------------------------------------------------------
__global__ __launch_bounds__(128) void upd_x_kernel(
    float* __restrict__ x, const float* __restrict__ v,
    const float* __restrict__ S, const float* __restrict__ Tt,
    const float* __restrict__ Q,
    const float* __restrict__ maskp, int maskInv,
    const float* __restrict__ epsp, float* __restrict__ ld, int fwd)
{
  int row = blockIdx.x;
  int c = threadIdx.x << 2;
  size_t off = (size_t)row * ND + c;
  float eps = epsp[0];
  float4 x4 = *reinterpret_cast<float4*>(x + off);
  float4 v4 = *reinterpret_cast<const float4*>(v + off);
  float4 s4 = *reinterpret_cast<const float4*>(S + off);
  float4 t4 = *reinterpret_cast<const float4*>(Tt + off);
  float4 q4 = *reinterpret_cast<const float4*>(Q + off);
  float4 m4 = *reinterpret_cast<const float4*>(maskp + c);
  float xx[4] = {x4.x, x4.y, x4.z, x4.w};
  float vv[4] = {v4.x, v4.y, v4.z, v4.w};
  float ss[4] = {s4.x, s4.y, s4.z, s4.w};
  float tz[4] = {t4.x, t4.y, t4.z, t4.w};
  float qq[4] = {q4.x, q4.y, q4.z, q4.w};
  float mm[4] = {m4.x, m4.y, m4.z, m4.w};
  float scsum = 0.f;
#pragma unroll
  for (int j = 0; j < 4; ++j) {
    float m = maskInv ? 1.f - mm[j] : mm[j];
    float mb = 1.f - m;
    float es = eps * ss[j];
    float F = vv[j] * expf(eps * qq[j]) + tz[j];
    float xn;
    if (fwd) {
      xn = m * xx[j] + mb * (xx[j] * expf(es) + eps * F);
      scsum += mb * es;
    } else {
      xn = m * xx[j] + mb * (expf(-es) * (xx[j] - eps * F));
      scsum -= mb * es;
    }
    xx[j] = wrap_angle(xn);
  }
  *reinterpret_cast<float4*>(x + off) = make_float4(xx[0], xx[1], xx[2], xx[3]);
  for (int o = 32; o > 0; o >>= 1) scsum += __shfl_down(scsum, o);
  __shared__ float part[2];
  if ((threadIdx.x & 63) == 0) part[threadIdx.x >> 6] = scsum;
  __syncthreads();
  if (threadIdx.x == 0) ld[row] += part[0] + part[1];
}

// ---------------------------------------------------------------------------
// finalize: pick direction, compute H_init/H_prop, Metropolis accept, outputs.
// One block (256 thr) per sample.
// ---------------------------------------------------------------------------
__global__ __launch_bounds__(256) void finalize_kernel(
    const float* __restrict__ x_in, const float* __restrict__ v_in,
    const float* __restrict__ xf, const float* __restrict__ vf,
    const float* __restrict__ ldf,
    const float* __restrict__ xb, const float* __restrict__ vb,
    const float* __restrict__ ldb,
    const float* __restrict__ rdir, const float* __restrict__ racc,
    const float* __restrict__ betap,
    float* __restrict__ out_x, float* __restrict__ out_px,
    float* __restrict__ out_sld)
{
  int b = blockIdx.x, t = threadIdx.x;
  bool fwd = rdir[b] < 0.5f;
  const float* xp = (fwd ? xf : xb) + (size_t)b * ND;
  const float* vp = (fwd ? vf : vb) + (size_t)b * ND;
  const float* vi = v_in + (fwd ? (size_t)0 : (size_t)NB * ND) + (size_t)b * ND;
  float sld = fwd ? ldf[b] : ldb[b];
  __shared__ float xs0[512], xs1[512];
  const float* xr = x_in + (size_t)b * ND;
  xs0[t] = xr[t]; xs0[t + 256] = xr[t + 256];
  xs1[t] = xp[t]; xs1[t + 256] = xp[t + 256];
  __syncthreads();
  int tt = t >> 4, l = t & 15;
  int i00 = t * 2, i01 = t * 2 + 1;
  int i10 = (tt * 16 + ((l + 1) & 15)) * 2;
  int i11 = (((tt + 1) & 15) * 16 + l) * 2 + 1;
  float p0 = xs0[i00] - xs0[i01] - xs0[i10] + xs0[i11];
  float p1 = xs1[i00] - xs1[i01] - xs1[i10] + xs1[i11];
  float r0 = 1.f - cosf(p0);
  float r1 = 1.f - cosf(p1);
  float a0v = vi[t], a1v = vi[t + 256];
  float b0v = vp[t], b1v = vp[t + 256];
  float svi = a0v * a0v + a1v * a1v;
  float svp = b0v * b0v + b1v * b1v;
  for (int o = 32; o > 0; o >>= 1) {
    r0  += __shfl_down(r0, o);
    r1  += __shfl_down(r1, o);
    svi += __shfl_down(svi, o);
    svp += __shfl_down(svp, o);
  }
  __shared__ float red[4][4];
  if ((t & 63) == 0) {
    int w = t >> 6;
    red[w][0] = r0; red[w][1] = r1; red[w][2] = svi; red[w][3] = svp;
  }
  __syncthreads();
  __shared__ float px_s;
  if (t == 0) {
    float R0 = 0, R1 = 0, SI = 0, SP = 0;
    for (int w = 0; w < 4; ++w) {
      R0 += red[w][0]; R1 += red[w][1]; SI += red[w][2]; SP += red[w][3];
    }
    float beta = betap[0];
    float h_init = beta * R0 + 0.5f * SI;
    float h_prop = beta * R1 + 0.5f * SP;
    px_s = expf(fminf(h_init - h_prop + sld, 0.f));
  }
  __syncthreads();
  float px = px_s;
  bool ma = racc[b] < px;
  float* ox = out_x + (size_t)b * ND;
  ox[t]       = wrap_angle(ma ? xs1[t]       : xs0[t]);
  ox[t + 256] = wrap_angle(ma ? xs1[t + 256] : xs0[t + 256]);
  if (t == 0) {
    out_px[b] = px;
    out_sld[b] = ma ? sld : 0.f;
  }
}

}  // namespace

extern "C" void kernel_launch(void* const* d_in, const int* in_sizes, int n_in,
                              void* d_out, int out_size, void* d_ws, size_t ws_size,
                              hipStream_t stream)
{
  const float* x_in = (const float*)d_in[0];
  const float* v_in = (const float*)d_in[1];
  const float* epsp = (const float*)d_in[2];
  const float* betap = (const float*)d_in[3];
  const float* rdir = (const float*)d_in[4];
  const float* racc = (const float*)d_in[5];
  const float* masks = (const float*)d_in[6];
  const float* XP[10];
  const float* VP[10];
  for (int i = 0; i < 10; ++i) {
    XP[i] = (const float*)d_in[7 + i];
    VP[i] = (const float*)d_in[17 + i];
  }

  float* p = (float*)d_ws;
  auto alloc = [&](size_t n) { float* r = p; p += n; return r; };
  float* xf = alloc((size_t)NB * ND);
  float* vf = alloc((size_t)NB * ND);
  float* xb = alloc((size_t)NB * ND);
  float* vb = alloc((size_t)NB * ND);
  float* ldf = alloc(NB);
  float* ldb = alloc(NB);
  float* g  = alloc((size_t)NB * ND);
  float* h1 = alloc((size_t)NB * NH);
  float* h2 = alloc((size_t)NB * NH);
  float* Sb = alloc((size_t)NB * ND);
  float* Tb = alloc((size_t)NB * ND);
  float* Qb = alloc((size_t)NB * ND);

  hipMemcpyAsync(xf, x_in, (size_t)NB * ND * 4, hipMemcpyDeviceToDevice, stream);
  hipMemcpyAsync(vf, v_in, (size_t)NB * ND * 4, hipMemcpyDeviceToDevice, stream);
  hipMemcpyAsync(xb, x_in, (size_t)NB * ND * 4, hipMemcpyDeviceToDevice, stream);
  hipMemcpyAsync(vb, v_in + (size_t)NB * ND, (size_t)NB * ND * 4,
                 hipMemcpyDeviceToDevice, stream);
  hipMemsetAsync(ldf, 0, NB * 4, stream);
  hipMemsetAsync(ldb, 0, NB * 4, stream);

  dim3 g2(16, 16), gs(8, 16, 3);

  auto run_net = [&](const float* A0, int lda0, const float* A1, int lda1,
                     const float* mk, int minv, const float* const* P) {
    gemm64<<<g2, 256, 0, stream>>>(A0, lda0, A1, lda1, mk, minv,
                                   P[0], NH, P[1], h1, NH, 1);
    gemm64<<<g2, 256, 0, stream>>>(h1, NH, h1 + ND, NH, nullptr, 0,
                                   P[2], NH, P[3], h2, NH, 1);
    stq_gemm<<<gs, 256, 0, stream>>>(h2, P[4], P[5], P[6], P[7], P[8], P[9],
                                     Sb, Tb, Qb);
  };

  for (int dir = 0; dir < 2; ++dir) {
    int fwd = (dir == 0) ? 1 : 0;
    float* xc = fwd ? xf : xb;
    float* vc = fwd ? vf : vb;
    float* lc = fwd ? ldf : ldb;
    for (int s = 0; s < NSTEPS_C; ++s) {
      const float* m = masks + (size_t)(fwd ? s : NSTEPS_C - 1 - s) * ND;
      // v half-step
      grad_kernel<<<NB, 256, 0, stream>>>(xc, g, betap);
      run_net(xc, ND, g, ND, nullptr, 0, VP);
      upd_v_kernel<<<NB, 128, 0, stream>>>(vc, g, Sb, Tb, Qb, epsp, lc, fwd);
      // two x sub-steps; fwd: m then 1-m ; bwd: 1-m then m
      int firstInv = fwd ? 0 : 1;
      for (int half = 0; half < 2; ++half) {
        int minv = (half == 0) ? firstInv : 1 - firstInv;
        run_net(vc, ND, xc, ND, m, minv, XP);
        upd_x_kernel<<<NB, 128, 0, stream>>>(xc, vc, Sb, Tb, Qb, m, minv,
                                             epsp, lc, fwd);
      }
      // v half-step
      grad_kernel<<<NB, 256, 0, stream>>>(xc, g, betap);
      run_net(xc, ND, g, ND, nullptr, 0, VP);
      upd_v_kernel<<<NB, 128, 0, stream>>>(vc, g, Sb, Tb, Qb, epsp, lc, fwd);
    }
  }

  float* out_x = (float*)d_out;
  float* out_px = out_x + (size_t)NB * ND;
  float* out_sld = out_px + NB;
  finalize_kernel<<<NB, 256, 0, stream>>>(x_in, v_in, xf, vf, ldf, xb, vb, ldb,
                                          rdir, racc, betap,
                                          out_x, out_px, out_sld);
}

// Round 3
// 3758.737 us; speedup vs baseline: 4.2313x; 4.2313x over previous
//
#include <hip/hip_runtime.h>
#include <math.h>

namespace {

constexpr int NB = 1024;     // per-direction batch
constexpr int ND = 512;      // XDIM
constexpr int NH = 1024;     // hidden
constexpr int NM = 2048;     // stacked batch (fwd rows 0..1023, bwd rows 1024..2047)
constexpr int KTOT = 1024;   // GEMM K for all layers

typedef __attribute__((ext_vector_type(8))) short short8;
typedef __attribute__((ext_vector_type(4))) float floatx4;

__device__ __forceinline__ unsigned short f2bf(float f) {
  unsigned int u = __float_as_uint(f);
  unsigned int r = (u + 0x7FFFu + ((u >> 16) & 1u)) >> 16;
  return (unsigned short)r;
}
__device__ __forceinline__ float bf2f(unsigned short h) {
  return __uint_as_float(((unsigned int)h) << 16);
}

__device__ __forceinline__ float wrap_angle(float x) {
  const float PI_F = 3.14159265358979323846f;
  const float TWO_PI = 6.28318530717958647692f;
  const float INV_TWO_PI = 0.15915494309189533577f;
  float y = x + PI_F;
  float r = y - TWO_PI * floorf(y * INV_TWO_PI);
  return r - PI_F;
}

// ---------------------------------------------------------------------------
// Weight prep: split-transpose f32 [K][N] -> bf16 hi/lo [rowoff+n][K]
// ---------------------------------------------------------------------------
__global__ __launch_bounds__(256) void tcvt_k(
    const float* __restrict__ in, int N,
    unsigned short* __restrict__ out_hi, unsigned short* __restrict__ out_lo,
    int rowoff)
{
  __shared__ float t[32][33];
  int tx = threadIdx.x, ty = threadIdx.y;
  int k0 = blockIdx.y * 32, n0 = blockIdx.x * 32;
#pragma unroll
  for (int i = 0; i < 4; ++i)
    t[ty * 4 + i][tx] = in[(size_t)(k0 + ty * 4 + i) * N + n0 + tx];
  __syncthreads();
#pragma unroll
  for (int i = 0; i < 4; ++i) {
    float f = t[tx][ty * 4 + i];
    unsigned short h = f2bf(f);
    unsigned short l = f2bf(f - bf2f(h));
    size_t idx = (size_t)(rowoff + n0 + ty * 4 + i) * KTOT + k0 + tx;
    out_hi[idx] = h;
    out_lo[idx] = l;
  }
}

// ---------------------------------------------------------------------------
// Split-bf16 MFMA GEMM (3-term: Ah*Bh + Ah*Bl + Al*Bh), f32 in/out.
// M=2048 (grid.y=32), tile 64x64, BK=64, 256 thr (4 waves), wave = 32x32
// via 2x2 16x16x32 fragments. LDS XOR-swizzled at 16B granule.
// AMODE 0: A = f32 [M][1024] (Af)
// AMODE 1: A = concat(A0,A1), f32 [M][512] halves, no mask
// AMODE 2: like 1, A1 *= mask (maskF rows<NB, maskB rows>=NB, inv flags)
// ACT 1: tanh everywhere. ACT 2: tanh unless col in [512,1024) (STQ mode).
// ---------------------------------------------------------------------------
template <int AMODE, int ACT>
__global__ __launch_bounds__(256) void gemm_k(
    const float* __restrict__ Af,
    const float* __restrict__ A0, const float* __restrict__ A1,
    const float* __restrict__ maskF, int invF,
    const float* __restrict__ maskB, int invB,
    const unsigned short* __restrict__ Bh,
    const unsigned short* __restrict__ Bl,
    const float* __restrict__ bias,
    float* __restrict__ outp, int ldo)
{
  __shared__ __align__(16) unsigned short As_h[64 * 64];
  __shared__ __align__(16) unsigned short As_l[64 * 64];
  __shared__ __align__(16) unsigned short Bs_h[64 * 64];
  __shared__ __align__(16) unsigned short Bs_l[64 * 64];
  const int tid = threadIdx.x;
  const int row0 = blockIdx.y * 64, col0 = blockIdx.x * 64;
  const int r0 = tid >> 3, r1 = 32 + (tid >> 3), kg = tid & 7;

  auto loadA = [&](int rl, int kb, short8& hi, short8& lo) {
    float f[8];
    if constexpr (AMODE == 0) {
      const float* src = Af + (size_t)(row0 + rl) * KTOT + kb + kg * 8;
      float4 x0 = *reinterpret_cast<const float4*>(src);
      float4 x1 = *reinterpret_cast<const float4*>(src + 4);
      f[0] = x0.x; f[1] = x0.y; f[2] = x0.z; f[3] = x0.w;
      f[4] = x1.x; f[5] = x1.y; f[6] = x1.z; f[7] = x1.w;
    } else {
      int gr = row0 + rl;
      const float* src = (kb < 512)
          ? (A0 + (size_t)gr * 512 + kb + kg * 8)
          : (A1 + (size_t)gr * 512 + (kb - 512) + kg * 8);
      float4 x0 = *reinterpret_cast<const float4*>(src);
      float4 x1 = *reinterpret_cast<const float4*>(src + 4);
      f[0] = x0.x; f[1] = x0.y; f[2] = x0.z; f[3] = x0.w;
      f[4] = x1.x; f[5] = x1.y; f[6] = x1.z; f[7] = x1.w;
      if constexpr (AMODE == 2) {
        if (kb >= 512) {
          const float* mp = (gr < NB) ? maskF : maskB;
          int inv = (gr < NB) ? invF : invB;
          int mo = (kb - 512) + kg * 8;
          float4 m0 = *reinterpret_cast<const float4*>(mp + mo);
          float4 m1 = *reinterpret_cast<const float4*>(mp + mo + 4);
          float mv[8] = {m0.x, m0.y, m0.z, m0.w, m1.x, m1.y, m1.z, m1.w};
#pragma unroll
          for (int j = 0; j < 8; ++j) f[j] *= inv ? (1.f - mv[j]) : mv[j];
        }
      }
    }
#pragma unroll
    for (int j = 0; j < 8; ++j) {
      unsigned short h = f2bf(f[j]);
      hi[j] = (short)h;
      lo[j] = (short)f2bf(f[j] - bf2f(h));
    }
  };
  auto loadB = [&](int rl, int kb, short8& hi, short8& lo) {
    size_t idx = (size_t)(col0 + rl) * KTOT + kb + kg * 8;
    hi = *reinterpret_cast<const short8*>(Bh + idx);
    lo = *reinterpret_cast<const short8*>(Bl + idx);
  };

  floatx4 acc[2][2];
#pragma unroll
  for (int i = 0; i < 2; ++i)
#pragma unroll
    for (int j = 0; j < 2; ++j) acc[i][j] = (floatx4)0.f;

  const int lane = tid & 63, w = tid >> 6, wr = w >> 1, wc = w & 1;
  const int rsel = lane & 15, ksel = lane >> 4;
  const int sg0 = (kg ^ (r0 & 7)) * 8, sg1 = (kg ^ (r1 & 7)) * 8;

  short8 a0h, a0l, a1h, a1l, b0h, b0l, b1h, b1l;
  loadA(r0, 0, a0h, a0l); loadA(r1, 0, a1h, a1l);
  loadB(r0, 0, b0h, b0l); loadB(r1, 0, b1h, b1l);

  for (int kt = 0; kt < 16; ++kt) {
    *reinterpret_cast<short8*>(As_h + r0 * 64 + sg0) = a0h;
    *reinterpret_cast<short8*>(As_l + r0 * 64 + sg0) = a0l;
    *reinterpret_cast<short8*>(As_h + r1 * 64 + sg1) = a1h;
    *reinterpret_cast<short8*>(As_l + r1 * 64 + sg1) = a1l;
    *reinterpret_cast<short8*>(Bs_h + r0 * 64 + sg0) = b0h;
    *reinterpret_cast<short8*>(Bs_l + r0 * 64 + sg0) = b0l;
    *reinterpret_cast<short8*>(Bs_h + r1 * 64 + sg1) = b1h;
    *reinterpret_cast<short8*>(Bs_l + r1 * 64 + sg1) = b1l;
    __syncthreads();
    if (kt < 15) {
      int kb = (kt + 1) * 64;
      loadA(r0, kb, a0h, a0l); loadA(r1, kb, a1h, a1l);
      loadB(r0, kb, b0h, b0l); loadB(r1, kb, b1h, b1l);
    }
#pragma unroll
    for (int ks = 0; ks < 2; ++ks) {
      const int kgr = ks * 4 + ksel;
      short8 afh[2], afl[2], bqh[2], bql[2];
#pragma unroll
      for (int i = 0; i < 2; ++i) {
        int ra = wr * 32 + i * 16 + rsel;
        int ao = ra * 64 + ((kgr ^ (ra & 7)) * 8);
        afh[i] = *reinterpret_cast<const short8*>(As_h + ao);
        afl[i] = *reinterpret_cast<const short8*>(As_l + ao);
        int rb = wc * 32 + i * 16 + rsel;
        int bo = rb * 64 + ((kgr ^ (rb & 7)) * 8);
        bqh[i] = *reinterpret_cast<const short8*>(Bs_h + bo);
        bql[i] = *reinterpret_cast<const short8*>(Bs_l + bo);
      }
#pragma unroll
      for (int i = 0; i < 2; ++i)
#pragma unroll
        for (int j = 0; j < 2; ++j) {
          acc[i][j] = __builtin_amdgcn_mfma_f32_16x16x32_bf16(
              afh[i], bqh[j], acc[i][j], 0, 0, 0);
          acc[i][j] = __builtin_amdgcn_mfma_f32_16x16x32_bf16(
              afh[i], bql[j], acc[i][j], 0, 0, 0);
          acc[i][j] = __builtin_amdgcn_mfma_f32_16x16x32_bf16(
              afl[i], bqh[j], acc[i][j], 0, 0, 0);
        }
    }
    __syncthreads();
  }

#pragma unroll
  for (int i = 0; i < 2; ++i) {
#pragma unroll
    for (int j = 0; j < 2; ++j) {
      int gr = row0 + wr * 32 + i * 16 + ksel * 4;
      int gc = col0 + wc * 32 + j * 16 + rsel;
      float bb = bias[gc];
      bool dt = (ACT == 1) || (ACT == 2 && !(gc >= 512 && gc < 1024));
#pragma unroll
      for (int rg = 0; rg < 4; ++rg) {
        float v = acc[i][j][rg] + bb;
        if (dt) v = tanhf(v);
        outp[(size_t)(gr + rg) * ldo + gc] = v;
      }
    }
  }
}

// ---------------------------------------------------------------------------
// grad of action into g (128 threads per row)
// ---------------------------------------------------------------------------
__device__ __forceinline__ void grad_from_lds(
    const float* xsh, float* sp, float beta, int row, float* __restrict__ g)
{
  int s0 = threadIdx.x * 2;
#pragma unroll
  for (int u = 0; u < 2; ++u) {
    int s = s0 + u, tt = s >> 4, l = s & 15;
    float p = xsh[s * 2] - xsh[s * 2 + 1]
            - xsh[(tt * 16 + ((l + 1) & 15)) * 2]
            + xsh[(((tt + 1) & 15) * 16 + l) * 2 + 1];
    sp[s] = sinf(p);
  }
  __syncthreads();
  float* gr = g + (size_t)row * ND;
#pragma unroll
  for (int u = 0; u < 2; ++u) {
    int s = s0 + u, tt = s >> 4, l = s & 15;
    float g0 = beta * (sp[s] - sp[tt * 16 + ((l - 1) & 15)]);
    float g1 = beta * (sp[((tt - 1) & 15) * 16 + l] - sp[s]);
    gr[s * 2] = g0;
    gr[s * 2 + 1] = g1;
  }
}

__global__ __launch_bounds__(128) void grad_k(
    const float* __restrict__ xs, const float* __restrict__ betap,
    float* __restrict__ g)
{
  __shared__ float xsh[512];
  __shared__ float sp[256];
  int row = blockIdx.x, c = threadIdx.x << 2;
  float4 x4 = *reinterpret_cast<const float4*>(xs + (size_t)row * ND + c);
  xsh[c] = x4.x; xsh[c + 1] = x4.y; xsh[c + 2] = x4.z; xsh[c + 3] = x4.w;
  __syncthreads();
  grad_from_lds(xsh, sp, betap[0], row, g);
}

// ---------------------------------------------------------------------------
// v update; STQ is f32 [row][1536] = [S|T|Q]
// ---------------------------------------------------------------------------
__global__ __launch_bounds__(128) void upd_v_k(
    float* __restrict__ vs, const float* __restrict__ g,
    const float* __restrict__ STQ,
    const float* __restrict__ epsp, float* __restrict__ ld)
{
  int row = blockIdx.x;
  bool fwd = row < NB;
  int c = threadIdx.x << 2;
  float eps = epsp[0];
  size_t off = (size_t)row * ND + c;
  const float* sr = STQ + (size_t)row * 1536;
  float4 v4 = *reinterpret_cast<float4*>(vs + off);
  float4 g4 = *reinterpret_cast<const float4*>(g + off);
  float4 S4 = *reinterpret_cast<const float4*>(sr + c);
  float4 T4 = *reinterpret_cast<const float4*>(sr + 512 + c);
  float4 Q4 = *reinterpret_cast<const float4*>(sr + 1024 + c);
  float vv[4] = {v4.x, v4.y, v4.z, v4.w};
  float gg[4] = {g4.x, g4.y, g4.z, g4.w};
  float ss[4] = {S4.x, S4.y, S4.z, S4.w};
  float tt[4] = {T4.x, T4.y, T4.z, T4.w};
  float qq[4] = {Q4.x, Q4.y, Q4.z, Q4.w};
  float scsum = 0.f;
#pragma unroll
  for (int j = 0; j < 4; ++j) {
    float sc = (fwd ? 0.5f : -0.5f) * eps * ss[j];
    float F = gg[j] * expf(eps * qq[j]) + tt[j];
    vv[j] = fwd ? vv[j] * expf(sc) - 0.5f * eps * F
                : expf(sc) * (vv[j] + 0.5f * eps * F);
    scsum += sc;
  }
  *reinterpret_cast<float4*>(vs + off) = make_float4(vv[0], vv[1], vv[2], vv[3]);
  for (int o = 32; o > 0; o >>= 1) scsum += __shfl_down(scsum, o);
  __shared__ float part[2];
  if ((threadIdx.x & 63) == 0) part[threadIdx.x >> 6] = scsum;
  __syncthreads();
  if (threadIdx.x == 0) ld[row] += part[0] + part[1];
}

// ---------------------------------------------------------------------------
// x update + fused grad recompute (g of the NEW x)
// ---------------------------------------------------------------------------
__global__ __launch_bounds__(128) void upd_x_k(
    float* __restrict__ xs, const float* __restrict__ vs,
    const float* __restrict__ STQ,
    const float* __restrict__ maskF, int invF,
    const float* __restrict__ maskB, int invB,
    const float* __restrict__ epsp, const float* __restrict__ betap,
    float* __restrict__ g, float* __restrict__ ld)
{
  __shared__ float xsh[512];
  __shared__ float sp[256];
  int row = blockIdx.x;
  bool fwd = row < NB;
  const float* mk = fwd ? maskF : maskB;
  int inv = fwd ? invF : invB;
  int c = threadIdx.x << 2;
  float eps = epsp[0];
  size_t off = (size_t)row * ND + c;
  const float* sr = STQ + (size_t)row * 1536;
  float4 x4 = *reinterpret_cast<float4*>(xs + off);
  float4 v4 = *reinterpret_cast<const float4*>(vs + off);
  float4 m4 = *reinterpret_cast<const float4*>(mk + c);
  float4 S4 = *reinterpret_cast<const float4*>(sr + c);
  float4 T4 = *reinterpret_cast<const float4*>(sr + 512 + c);
  float4 Q4 = *reinterpret_cast<const float4*>(sr + 1024 + c);
  float xx[4] = {x4.x, x4.y, x4.z, x4.w};
  float vv[4] = {v4.x, v4.y, v4.z, v4.w};
  float mm[4] = {m4.x, m4.y, m4.z, m4.w};
  float ss[4] = {S4.x, S4.y, S4.z, S4.w};
  float tt[4] = {T4.x, T4.y, T4.z, T4.w};
  float qq[4] = {Q4.x, Q4.y, Q4.z, Q4.w};
  float scsum = 0.f;
  float xn[4];
#pragma unroll
  for (int j = 0; j < 4; ++j) {
    float m = inv ? 1.f - mm[j] : mm[j];
    float mb = 1.f - m;
    float es = eps * ss[j];
    float F = vv[j] * expf(eps * qq[j]) + tt[j];
    float t;
    if (fwd) {
      t = m * xx[j] + mb * (xx[j] * expf(es) + eps * F);
      scsum += mb * es;
    } else {
      t = m * xx[j] + mb * (expf(-es) * (xx[j] - eps * F));
      scsum -= mb * es;
    }
    xn[j] = wrap_angle(t);
    xsh[c + j] = xn[j];
  }
  *reinterpret_cast<float4*>(xs + off) = make_float4(xn[0], xn[1], xn[2], xn[3]);
  __syncthreads();
  grad_from_lds(xsh, sp, betap[0], row, g);
  for (int o = 32; o > 0; o >>= 1) scsum += __shfl_down(scsum, o);
  __shared__ float part[2];
  if ((threadIdx.x & 63) == 0) part[threadIdx.x >> 6] = scsum;
  __syncthreads();
  if (threadIdx.x == 0) ld[row] += part[0] + part[1];
}

// ---------------------------------------------------------------------------
// finalize (stacked state)
// ---------------------------------------------------------------------------
__global__ __launch_bounds__(256) void finalize_k(
    const float* __restrict__ x_in, const float* __restrict__ v_in,
    const float* __restrict__ xs, const float* __restrict__ vs,
    const float* __restrict__ ld,
    const float* __restrict__ rdir, const float* __restrict__ racc,
    const float* __restrict__ betap,
    float* __restrict__ out_x, float* __restrict__ out_px,
    float* __restrict__ out_sld)
{
  int b = blockIdx.x, t = threadIdx.x;
  bool fwd = rdir[b] < 0.5f;
  int prow = fwd ? b : NB + b;
  const float* xp = xs + (size_t)prow * ND;
  const float* vp = vs + (size_t)prow * ND;
  const float* vi = v_in + (size_t)(fwd ? 0 : NB) * ND + (size_t)b * ND;
  float sld = ld[prow];
  __shared__ float xs0[512], xs1[512];
  const float* xr = x_in + (size_t)b * ND;
  xs0[t] = xr[t]; xs0[t + 256] = xr[t + 256];
  xs1[t] = xp[t]; xs1[t + 256] = xp[t + 256];
  __syncthreads();
  int tt = t >> 4, l = t & 15;
  int i00 = t * 2, i01 = t * 2 + 1;
  int i10 = (tt * 16 + ((l + 1) & 15)) * 2;
  int i11 = (((tt + 1) & 15) * 16 + l) * 2 + 1;
  float p0 = xs0[i00] - xs0[i01] - xs0[i10] + xs0[i11];
  float p1 = xs1[i00] - xs1[i01] - xs1[i10] + xs1[i11];
  float r0 = 1.f - cosf(p0);
  float r1 = 1.f - cosf(p1);
  float a0v = vi[t], a1v = vi[t + 256];
  float b0v = vp[t], b1v = vp[t + 256];
  float svi = a0v * a0v + a1v * a1v;
  float svp = b0v * b0v + b1v * b1v;
  for (int o = 32; o > 0; o >>= 1) {
    r0  += __shfl_down(r0, o);
    r1  += __shfl_down(r1, o);
    svi += __shfl_down(svi, o);
    svp += __shfl_down(svp, o);
  }
  __shared__ float red[4][4];
  if ((t & 63) == 0) {
    int w = t >> 6;
    red[w][0] = r0; red[w][1] = r1; red[w][2] = svi; red[w][3] = svp;
  }
  __syncthreads();
  __shared__ float px_s;
  if (t == 0) {
    float R0 = 0, R1 = 0, SI = 0, SP = 0;
    for (int w = 0; w < 4; ++w) {
      R0 += red[w][0]; R1 += red[w][1]; SI += red[w][2]; SP += red[w][3];
    }
    float beta = betap[0];
    float h_init = beta * R0 + 0.5f * SI;
    float h_prop = beta * R1 + 0.5f * SP;
    px_s = expf(fminf(h_init - h_prop + sld, 0.f));
  }
  __syncthreads();
  float px = px_s;
  bool ma = racc[b] < px;
  float* ox = out_x + (size_t)b * ND;
  ox[t]       = wrap_angle(ma ? xs1[t]       : xs0[t]);
  ox[t + 256] = wrap_angle(ma ? xs1[t + 256] : xs0[t + 256]);
  if (t == 0) {
    out_px[b] = px;
    out_sld[b] = ma ? sld : 0.f;
  }
}

}  // namespace

extern "C" void kernel_launch(void* const* d_in, const int* in_sizes, int n_in,
                              void* d_out, int out_size, void* d_ws, size_t ws_size,
                              hipStream_t stream)
{
  const float* x_in = (const float*)d_in[0];
  const float* v_in = (const float*)d_in[1];
  const float* epsp = (const float*)d_in[2];
  const float* betap = (const float*)d_in[3];
  const float* rdir = (const float*)d_in[4];
  const float* racc = (const float*)d_in[5];
  const float* masks = (const float*)d_in[6];
  const float* xW1 = (const float*)d_in[7];
  const float* xb1 = (const float*)d_in[8];
  const float* xW2 = (const float*)d_in[9];
  const float* xb2 = (const float*)d_in[10];
  const float* xWs = (const float*)d_in[11];
  const float* xbs = (const float*)d_in[12];
  const float* xWt = (const float*)d_in[13];
  const float* xbt = (const float*)d_in[14];
  const float* xWq = (const float*)d_in[15];
  const float* xbq = (const float*)d_in[16];
  const float* vW1 = (const float*)d_in[17];
  const float* vb1 = (const float*)d_in[18];
  const float* vW2 = (const float*)d_in[19];
  const float* vb2 = (const float*)d_in[20];
  const float* vWs = (const float*)d_in[21];
  const float* vbs = (const float*)d_in[22];
  const float* vWt = (const float*)d_in[23];
  const float* vbt = (const float*)d_in[24];
  const float* vWq = (const float*)d_in[25];
  const float* vbq = (const float*)d_in[26];

  char* base = (char*)d_ws;
  auto alloc = [&](size_t bytes) {
    char* r = base;
    base += (bytes + 255) & ~(size_t)255;
    return r;
  };
  float* xs = (float*)alloc((size_t)NM * ND * 4);
  float* vs = (float*)alloc((size_t)NM * ND * 4);
  float* g  = (float*)alloc((size_t)NM * ND * 4);
  float* ld = (float*)alloc((size_t)NM * 4);
  float* h1  = (float*)alloc((size_t)NM * NH * 4);
  float* h2  = (float*)alloc((size_t)NM * NH * 4);
  float* STQ = (float*)alloc((size_t)NM * 1536 * 4);
  unsigned short* xW1h  = (unsigned short*)alloc((size_t)NH * KTOT * 2);
  unsigned short* xW1l  = (unsigned short*)alloc((size_t)NH * KTOT * 2);
  unsigned short* xW2h  = (unsigned short*)alloc((size_t)NH * KTOT * 2);
  unsigned short* xW2l  = (unsigned short*)alloc((size_t)NH * KTOT * 2);
  unsigned short* xWsh  = (unsigned short*)alloc((size_t)1536 * KTOT * 2);
  unsigned short* xWsl  = (unsigned short*)alloc((size_t)1536 * KTOT * 2);
  unsigned short* vW1h  = (unsigned short*)alloc((size_t)NH * KTOT * 2);
  unsigned short* vW1l  = (unsigned short*)alloc((size_t)NH * KTOT * 2);
  unsigned short* vW2h  = (unsigned short*)alloc((size_t)NH * KTOT * 2);
  unsigned short* vW2l  = (unsigned short*)alloc((size_t)NH * KTOT * 2);
  unsigned short* vWsh  = (unsigned short*)alloc((size_t)1536 * KTOT * 2);
  unsigned short* vWsl  = (unsigned short*)alloc((size_t)1536 * KTOT * 2);
  float* bstq_x = (float*)alloc(1536 * 4);
  float* bstq_v = (float*)alloc(1536 * 4);

  // ---- weight prep (once per launch; weights reused 20-80x) ----
  dim3 tb(32, 8);
  tcvt_k<<<dim3(32, 32), tb, 0, stream>>>(xW1, 1024, xW1h, xW1l, 0);
  tcvt_k<<<dim3(32, 32), tb, 0, stream>>>(xW2, 1024, xW2h, xW2l, 0);
  tcvt_k<<<dim3(16, 32), tb, 0, stream>>>(xWs, 512, xWsh, xWsl, 0);
  tcvt_k<<<dim3(16, 32), tb, 0, stream>>>(xWt, 512, xWsh, xWsl, 512);
  tcvt_k<<<dim3(16, 32), tb, 0, stream>>>(xWq, 512, xWsh, xWsl, 1024);
  tcvt_k<<<dim3(32, 32), tb, 0, stream>>>(vW1, 1024, vW1h, vW1l, 0);
  tcvt_k<<<dim3(32, 32), tb, 0, stream>>>(vW2, 1024, vW2h, vW2l, 0);
  tcvt_k<<<dim3(16, 32), tb, 0, stream>>>(vWs, 512, vWsh, vWsl, 0);
  tcvt_k<<<dim3(16, 32), tb, 0, stream>>>(vWt, 512, vWsh, vWsl, 512);
  tcvt_k<<<dim3(16, 32), tb, 0, stream>>>(vWq, 512, vWsh, vWsl, 1024);
  hipMemcpyAsync(bstq_x,        xbs, 512 * 4, hipMemcpyDeviceToDevice, stream);
  hipMemcpyAsync(bstq_x + 512,  xbt, 512 * 4, hipMemcpyDeviceToDevice, stream);
  hipMemcpyAsync(bstq_x + 1024, xbq, 512 * 4, hipMemcpyDeviceToDevice, stream);
  hipMemcpyAsync(bstq_v,        vbs, 512 * 4, hipMemcpyDeviceToDevice, stream);
  hipMemcpyAsync(bstq_v + 512,  vbt, 512 * 4, hipMemcpyDeviceToDevice, stream);
  hipMemcpyAsync(bstq_v + 1024, vbq, 512 * 4, hipMemcpyDeviceToDevice, stream);

  // ---- state init: rows 0..1023 fwd chain, 1024..2047 bwd chain ----
  hipMemcpyAsync(xs, x_in, (size_t)NB * ND * 4, hipMemcpyDeviceToDevice, stream);
  hipMemcpyAsync(xs + (size_t)NB * ND, x_in, (size_t)NB * ND * 4,
                 hipMemcpyDeviceToDevice, stream);
  hipMemcpyAsync(vs, v_in, (size_t)2 * NB * ND * 4, hipMemcpyDeviceToDevice, stream);
  hipMemsetAsync(ld, 0, NM * 4, stream);
  grad_k<<<NM, 128, 0, stream>>>(xs, betap, g);

  dim3 gL(16, 32), gS(24, 32);
  auto vnet = [&]() {
    gemm_k<1, 1><<<gL, 256, 0, stream>>>(
        nullptr, xs, g, nullptr, 0, nullptr, 0, vW1h, vW1l, vb1, h1, NH);
    gemm_k<0, 1><<<gL, 256, 0, stream>>>(
        h1, nullptr, nullptr, nullptr, 0, nullptr, 0, vW2h, vW2l, vb2, h2, NH);
    gemm_k<0, 2><<<gS, 256, 0, stream>>>(
        h2, nullptr, nullptr, nullptr, 0, nullptr, 0, vWsh, vWsl, bstq_v, STQ, 1536);
  };
  auto xnet = [&](const float* mF, int iF, const float* mB, int iB) {
    gemm_k<2, 1><<<gL, 256, 0, stream>>>(
        nullptr, vs, xs, mF, iF, mB, iB, xW1h, xW1l, xb1, h1, NH);
    gemm_k<0, 1><<<gL, 256, 0, stream>>>(
        h1, nullptr, nullptr, nullptr, 0, nullptr, 0, xW2h, xW2l, xb2, h2, NH);
    gemm_k<0, 2><<<gS, 256, 0, stream>>>(
        h2, nullptr, nullptr, nullptr, 0, nullptr, 0, xWsh, xWsl, bstq_x, STQ, 1536);
  };

  for (int s = 0; s < 10; ++s) {
    const float* mF = masks + (size_t)s * ND;
    const float* mB = masks + (size_t)(9 - s) * ND;
    // v half-step (g already matches current x)
    vnet();
    upd_v_k<<<NM, 128, 0, stream>>>(vs, g, STQ, epsp, ld);
    // x sub-step 1: fwd uses m, bwd uses 1-m
    xnet(mF, 0, mB, 1);
    upd_x_k<<<NM, 128, 0, stream>>>(xs, vs, STQ, mF, 0, mB, 1, epsp, betap, g, ld);
    // x sub-step 2: fwd uses 1-m, bwd uses m
    xnet(mF, 1, mB, 0);
    upd_x_k<<<NM, 128, 0, stream>>>(xs, vs, STQ, mF, 1, mB, 0, epsp, betap, g, ld);
    // v half-step
    vnet();
    upd_v_k<<<NM, 128, 0, stream>>>(vs, g, STQ, epsp, ld);
  }

  float* out_x = (float*)d_out;
  float* out_px = out_x + (size_t)NB * ND;
  float* out_sld = out_px + NB;
  finalize_k<<<NB, 256, 0, stream>>>(x_in, v_in, xs, vs, ld, rdir, racc, betap,
                                     out_x, out_px, out_sld);
}